// Round 1
// baseline (1076.854 us; speedup 1.0000x reference)
//
#include <hip/hip_runtime.h>
#include <hip/hip_bf16.h>

typedef __bf16 bf16x8 __attribute__((ext_vector_type(8)));
typedef float f32x4 __attribute__((ext_vector_type(4)));

#define EB 128  // edges per block

// round-to-nearest-even f32 -> bf16, packed pair into u32
__device__ __forceinline__ unsigned int pack2bf(float a, float b) {
    unsigned int ua = __float_as_uint(a);
    unsigned int ub = __float_as_uint(b);
    ua = (ua + 0x7fffu + ((ua >> 16) & 1u)) >> 16;
    ub = (ub + 0x7fffu + ((ub >> 16) & 1u)) & 0xffff0000u;
    return ua | ub;
}

__device__ __forceinline__ unsigned short f2bf(float v) {
    unsigned int u = __float_as_uint(v);
    return (unsigned short)((u + 0x7fffu + ((u >> 16) & 1u)) >> 16);
}

// ws[0..8191]      : W1t[c][k] = W1[k][c]  (c=0..63, k=0..127) bf16
// ws[8192..12287]  : W2t[o][c] = W2[c][o]  (o=0..63, c=0..63)  bf16
__global__ void prep_weights_kernel(const float* __restrict__ W1,
                                    const float* __restrict__ W2,
                                    unsigned short* __restrict__ ws) {
    int t = blockIdx.x * blockDim.x + threadIdx.x;
    if (t < 8192) {
        int c = t >> 7, k = t & 127;
        ws[t] = f2bf(W1[k * 64 + c]);
    } else if (t < 12288) {
        int i = t - 8192;
        int o = i >> 6, c = i & 63;
        ws[t] = f2bf(W2[c * 64 + o]);
    }
}

__global__ __launch_bounds__(256, 2)
void edgeconv_kernel(const float* __restrict__ x,
                     const int* __restrict__ ei,
                     const float* __restrict__ b1,
                     const float* __restrict__ b2,
                     const unsigned short* __restrict__ ws,
                     float* __restrict__ out,
                     int E) {
    // F: [128 edges][128 feat] bf16, 256B rows, 16B-chunk XOR swizzle by (row&7)
    __shared__ __align__(16) unsigned char sF[EB * 256];
    // H1: [128 edges][64 ch] bf16, 128B rows, same swizzle
    __shared__ __align__(16) unsigned char sH[EB * 128];
    __shared__ int sDst[EB];

    const int tid  = threadIdx.x;
    const int lane = tid & 63;
    const int w    = tid >> 6;   // wave 0..3
    const int ln   = lane & 15;
    const int rg   = lane >> 4;  // 0..3

    // ---------------- gather: build F = [xi | xj - xi] in bf16 ----------------
    {
        const int e = tid >> 1;      // edge within block (2 threads/edge)
        const int h = tid & 1;       // half of the 64-ch row
        long g = (long)blockIdx.x * EB + e;
        int s_ = 0, d_ = 0;
        if (g < (long)E) { s_ = ei[g]; d_ = ei[(long)E + g]; }
        if (h == 0) sDst[e] = d_;

        const float4* xi4 = (const float4*)(x + (long)d_ * 64 + h * 32);
        const float4* xj4 = (const float4*)(x + (long)s_ * 64 + h * 32);
        float ai[32], aj[32];
        #pragma unroll
        for (int q = 0; q < 8; ++q) {
            float4 v = xi4[q];
            ai[q * 4 + 0] = v.x; ai[q * 4 + 1] = v.y;
            ai[q * 4 + 2] = v.z; ai[q * 4 + 3] = v.w;
        }
        #pragma unroll
        for (int q = 0; q < 8; ++q) {
            float4 v = xj4[q];
            aj[q * 4 + 0] = v.x; aj[q * 4 + 1] = v.y;
            aj[q * 4 + 2] = v.z; aj[q * 4 + 3] = v.w;
        }

        unsigned char* rowp = sF + e * 256;
        const unsigned int swz = (unsigned int)(e & 7) << 4;
        #pragma unroll
        for (int q = 0; q < 4; ++q) {
            uint4 u;
            u.x = pack2bf(ai[q * 8 + 0], ai[q * 8 + 1]);
            u.y = pack2bf(ai[q * 8 + 2], ai[q * 8 + 3]);
            u.z = pack2bf(ai[q * 8 + 4], ai[q * 8 + 5]);
            u.w = pack2bf(ai[q * 8 + 6], ai[q * 8 + 7]);
            *(uint4*)(rowp + ((((unsigned)(h * 4 + q)) << 4) ^ swz)) = u;
            uint4 ud;
            ud.x = pack2bf(aj[q * 8 + 0] - ai[q * 8 + 0], aj[q * 8 + 1] - ai[q * 8 + 1]);
            ud.y = pack2bf(aj[q * 8 + 2] - ai[q * 8 + 2], aj[q * 8 + 3] - ai[q * 8 + 3]);
            ud.z = pack2bf(aj[q * 8 + 4] - ai[q * 8 + 4], aj[q * 8 + 5] - ai[q * 8 + 5]);
            ud.w = pack2bf(aj[q * 8 + 6] - ai[q * 8 + 6], aj[q * 8 + 7] - ai[q * 8 + 7]);
            *(uint4*)(rowp + ((((unsigned)(8 + h * 4 + q)) << 4) ^ swz)) = ud;
        }
    }

    // ---------------- weight fragments (registers, from d_ws) ----------------
    // GEMM1 (transposed): H1^T = W1^T @ F^T.  A = W1^T tile: lane holds
    // row c = ct*16+ln, cols k = kt*32+rg*8..+7  -> contiguous 16B in W1t.
    bf16x8 w1f[4][4];
    bf16x8 w2f[4][2];
    {
        const bf16x8* wsv = (const bf16x8*)ws;
        #pragma unroll
        for (int ct = 0; ct < 4; ++ct)
            #pragma unroll
            for (int kt = 0; kt < 4; ++kt)
                w1f[ct][kt] = wsv[(ct * 16 + ln) * 16 + kt * 4 + rg];
        #pragma unroll
        for (int ot = 0; ot < 4; ++ot)
            #pragma unroll
            for (int kt = 0; kt < 2; ++kt)
                w2f[ot][kt] = wsv[1024 + (ot * 16 + ln) * 8 + kt * 4 + rg];
    }

    __syncthreads();

    // ---------------- GEMM1: H1^T = W1^T @ F^T ----------------
    // wave w owns edge-tiles et = 2w, 2w+1  (e in [w*32, w*32+32))
    f32x4 acc[2][4];
    #pragma unroll
    for (int eti = 0; eti < 2; ++eti)
        #pragma unroll
        for (int ct = 0; ct < 4; ++ct)
            acc[eti][ct] = (f32x4){0.f, 0.f, 0.f, 0.f};

    #pragma unroll
    for (int kt = 0; kt < 4; ++kt) {
        #pragma unroll
        for (int eti = 0; eti < 2; ++eti) {
            const int e = (w * 2 + eti) * 16 + ln;
            bf16x8 bf = *(const bf16x8*)(sF + e * 256 +
                           (((unsigned)(kt * 64 + rg * 16)) ^ ((unsigned)(e & 7) << 4)));
            #pragma unroll
            for (int ct = 0; ct < 4; ++ct)
                acc[eti][ct] = __builtin_amdgcn_mfma_f32_16x16x32_bf16(
                    w1f[ct][kt], bf, acc[eti][ct], 0, 0, 0);
        }
    }

    // ---------------- epilogue1: bias + relu -> bf16 -> sH ----------------
    // C layout: col(e) = ln, row(c) = rg*4 + r  (per ct tile)
    #pragma unroll
    for (int eti = 0; eti < 2; ++eti) {
        const int e = (w * 2 + eti) * 16 + ln;
        unsigned char* rowp = sH + e * 128;
        const unsigned int swz = (unsigned int)(e & 7) << 4;
        #pragma unroll
        for (int ct = 0; ct < 4; ++ct) {
            const int c0 = ct * 16 + rg * 4;
            float v0 = fmaxf(acc[eti][ct][0] + b1[c0 + 0], 0.f);
            float v1 = fmaxf(acc[eti][ct][1] + b1[c0 + 1], 0.f);
            float v2 = fmaxf(acc[eti][ct][2] + b1[c0 + 2], 0.f);
            float v3 = fmaxf(acc[eti][ct][3] + b1[c0 + 3], 0.f);
            uint2 u;
            u.x = pack2bf(v0, v1);
            u.y = pack2bf(v2, v3);
            *(uint2*)(rowp + (((unsigned)(c0 * 2)) ^ swz)) = u;
        }
    }

    // ---------------- GEMM2: H2^T = W2^T @ H1^T ----------------
    // sH rows written/read are wave-local (e in [w*32,w*32+32)) -> no barrier.
    f32x4 acc2[2][4];
    #pragma unroll
    for (int eti = 0; eti < 2; ++eti)
        #pragma unroll
        for (int ot = 0; ot < 4; ++ot)
            acc2[eti][ot] = (f32x4){0.f, 0.f, 0.f, 0.f};

    #pragma unroll
    for (int kt = 0; kt < 2; ++kt) {
        #pragma unroll
        for (int eti = 0; eti < 2; ++eti) {
            const int e = (w * 2 + eti) * 16 + ln;
            bf16x8 bf = *(const bf16x8*)(sH + e * 128 +
                           (((unsigned)(kt * 64 + rg * 16)) ^ ((unsigned)(e & 7) << 4)));
            #pragma unroll
            for (int ot = 0; ot < 4; ++ot)
                acc2[eti][ot] = __builtin_amdgcn_mfma_f32_16x16x32_bf16(
                    w2f[ot][kt], bf, acc2[eti][ot], 0, 0, 0);
        }
    }

    // ---------------- epilogue2: bias + relu -> atomic scatter-max ----------------
    #pragma unroll
    for (int eti = 0; eti < 2; ++eti) {
        const int e = (w * 2 + eti) * 16 + ln;
        long g = (long)blockIdx.x * EB + e;
        if (g < (long)E) {
            long base = (long)sDst[e] * 64;
            #pragma unroll
            for (int ot = 0; ot < 4; ++ot) {
                #pragma unroll
                for (int r = 0; r < 4; ++r) {
                    const int o = ot * 16 + rg * 4 + r;
                    float v = fmaxf(acc2[eti][ot][r] + b2[o], 0.f);
                    // v >= 0 -> int-bit compare is order-exact for IEEE f32
                    atomicMax((int*)out + base + o, __float_as_int(v));
                }
            }
        }
    }
}

extern "C" void kernel_launch(void* const* d_in, const int* in_sizes, int n_in,
                              void* d_out, int out_size, void* d_ws, size_t ws_size,
                              hipStream_t stream) {
    const float* x  = (const float*)d_in[0];
    const int*   ei = (const int*)d_in[1];
    const float* W1 = (const float*)d_in[2];
    const float* b1 = (const float*)d_in[3];
    const float* W2 = (const float*)d_in[4];
    const float* b2 = (const float*)d_in[5];
    float* out = (float*)d_out;

    const int E = in_sizes[1] / 2;
    unsigned short* ws = (unsigned short*)d_ws;

    hipMemsetAsync(d_out, 0, (size_t)out_size * sizeof(float), stream);
    prep_weights_kernel<<<48, 256, 0, stream>>>(W1, W2, ws);
    const int nb = (E + EB - 1) / EB;
    edgeconv_kernel<<<nb, 256, 0, stream>>>(x, ei, b1, b2, ws, out, E);
}

// Round 2
// 443.823 us; speedup vs baseline: 2.4263x; 2.4263x over previous
//
#include <hip/hip_runtime.h>
#include <hip/hip_bf16.h>

typedef __bf16 bf16x8 __attribute__((ext_vector_type(8)));
typedef float f32x4 __attribute__((ext_vector_type(4)));

#define EB 128  // edges per block
#define NSCAN 1024  // elements per scan block

// ---- ws layout (dword offsets) ----
// counts : [0, 100000)
// cursor : [100000, 200000)
// starts : [200000, 300001)
// bsum   : [300016, 300016+nb2)
// csr_src: [300160, 300160+E)
// csr_dst: [300160+E, 300160+2E)
// weights(bf16): dword [300160+2E, +3072)  (12288 bf16)
#define OFF_COUNTS 0
#define OFF_CURSOR 100000
#define OFF_STARTS 200000
#define OFF_BSUM   300016
#define OFF_CSR    300160

__device__ __forceinline__ unsigned int pack2bf(float a, float b) {
    unsigned int ua = __float_as_uint(a);
    unsigned int ub = __float_as_uint(b);
    ua = (ua + 0x7fffu + ((ua >> 16) & 1u)) >> 16;
    ub = (ub + 0x7fffu + ((ub >> 16) & 1u)) & 0xffff0000u;
    return ua | ub;
}
__device__ __forceinline__ unsigned short f2bf(float v) {
    unsigned int u = __float_as_uint(v);
    return (unsigned short)((u + 0x7fffu + ((u >> 16) & 1u)) >> 16);
}

__global__ void prep_weights_kernel(const float* __restrict__ W1,
                                    const float* __restrict__ W2,
                                    unsigned short* __restrict__ wout) {
    int t = blockIdx.x * blockDim.x + threadIdx.x;
    if (t < 8192) {
        int c = t >> 7, k = t & 127;
        wout[t] = f2bf(W1[k * 64 + c]);
    } else if (t < 12288) {
        int i = t - 8192;
        int o = i >> 6, c = i & 63;
        wout[t] = f2bf(W2[c * 64 + o]);
    }
}

__global__ void hist_kernel(const int* __restrict__ ei, int* __restrict__ counts, int E) {
    int t = blockIdx.x * blockDim.x + threadIdx.x;
    if (t < E) atomicAdd(&counts[ei[E + t]], 1);
}

__global__ void scanA_kernel(const int* __restrict__ counts, int* __restrict__ bsum, int N) {
    int b = blockIdx.x, t = threadIdx.x;
    int base = b * NSCAN + t * 4;
    int s = 0;
    #pragma unroll
    for (int q = 0; q < 4; ++q)
        if (base + q < N) s += counts[base + q];
    #pragma unroll
    for (int off = 1; off < 64; off <<= 1) s += __shfl_xor(s, off);
    __shared__ int wsum[4];
    if ((t & 63) == 0) wsum[t >> 6] = s;
    __syncthreads();
    if (t == 0) bsum[b] = wsum[0] + wsum[1] + wsum[2] + wsum[3];
}

__global__ void scanB_kernel(int* __restrict__ bsum, int* __restrict__ starts, int nb, int N, int E) {
    // single block; serial exclusive scan of nb (~98) block sums
    if (threadIdx.x == 0) {
        int run = 0;
        for (int i = 0; i < nb; ++i) {
            int v = bsum[i];
            bsum[i] = run;
            run += v;
        }
        starts[N] = E;
    }
}

__global__ void scanC_kernel(const int* __restrict__ counts, const int* __restrict__ bsum,
                             int* __restrict__ starts, int N) {
    int b = blockIdx.x, t = threadIdx.x;
    int lane = t & 63, w = t >> 6;
    int base = b * NSCAN + t * 4;
    int c[4];
    #pragma unroll
    for (int q = 0; q < 4; ++q)
        c[q] = (base + q < N) ? counts[base + q] : 0;
    int tot = c[0] + c[1] + c[2] + c[3];
    int inc = tot;
    #pragma unroll
    for (int off = 1; off < 64; off <<= 1) {
        int n = __shfl_up(inc, off);
        if (lane >= off) inc += n;
    }
    int excl = inc - tot;
    __shared__ int wtot[4];
    if (lane == 63) wtot[w] = inc;
    __syncthreads();
    int woff = 0;
    for (int i = 0; i < w; ++i) woff += wtot[i];
    int run = bsum[b] + woff + excl;
    #pragma unroll
    for (int q = 0; q < 4; ++q) {
        if (base + q < N) { starts[base + q] = run; run += c[q]; }
    }
}

__global__ void scatter_kernel(const int* __restrict__ ei, const int* __restrict__ starts,
                               int* __restrict__ cursor, int* __restrict__ csr_src,
                               int* __restrict__ csr_dst, int E) {
    int t = blockIdx.x * blockDim.x + threadIdx.x;
    if (t < E) {
        int s = ei[t], d = ei[E + t];
        int slot = atomicAdd(&cursor[d], 1);
        int p = starts[d] + slot;
        csr_src[p] = s;
        csr_dst[p] = d;
    }
}

__global__ __launch_bounds__(256, 4)
void edgeconv_kernel(const float* __restrict__ x,
                     const int* __restrict__ csr_src,
                     const int* __restrict__ csr_dst,
                     const int* __restrict__ starts,
                     const float* __restrict__ b1,
                     const float* __restrict__ b2,
                     const unsigned short* __restrict__ wbf,
                     float* __restrict__ out,
                     int E) {
    // F: [128 edges][128 feat] bf16, 256B rows, XOR-swizzled by (row&7)<<4.
    // Reused after GEMM1 as h2 f32 [128][64] (also 256B rows, same swizzle).
    __shared__ __align__(16) unsigned char sF[EB * 256];
    __shared__ __align__(16) unsigned char sH[EB * 128];  // h1 bf16 [128][64]

    const int tid  = threadIdx.x;
    const int lane = tid & 63;
    const int w    = tid >> 6;
    const int ln   = lane & 15;
    const int rg   = lane >> 4;
    const int p0   = blockIdx.x * EB;
    const int p1   = min(p0 + EB, E);

    // ---------------- gather (CSR order): F = [xi | xj - xi] bf16 ----------------
    {
        const int e = tid >> 1;
        const int h = tid & 1;
        const int p = p0 + e;
        int s_ = 0, d_ = 0;
        if (p < E) { s_ = csr_src[p]; d_ = csr_dst[p]; }

        const float4* xi4 = (const float4*)(x + (long)d_ * 64 + h * 32);
        const float4* xj4 = (const float4*)(x + (long)s_ * 64 + h * 32);
        float ai[32], aj[32];
        #pragma unroll
        for (int q = 0; q < 8; ++q) {
            float4 v = xi4[q];
            ai[q * 4 + 0] = v.x; ai[q * 4 + 1] = v.y;
            ai[q * 4 + 2] = v.z; ai[q * 4 + 3] = v.w;
        }
        #pragma unroll
        for (int q = 0; q < 8; ++q) {
            float4 v = xj4[q];
            aj[q * 4 + 0] = v.x; aj[q * 4 + 1] = v.y;
            aj[q * 4 + 2] = v.z; aj[q * 4 + 3] = v.w;
        }

        unsigned char* rowp = sF + e * 256;
        const unsigned int swz = (unsigned int)(e & 7) << 4;
        #pragma unroll
        for (int q = 0; q < 4; ++q) {
            uint4 u;
            u.x = pack2bf(ai[q * 8 + 0], ai[q * 8 + 1]);
            u.y = pack2bf(ai[q * 8 + 2], ai[q * 8 + 3]);
            u.z = pack2bf(ai[q * 8 + 4], ai[q * 8 + 5]);
            u.w = pack2bf(ai[q * 8 + 6], ai[q * 8 + 7]);
            *(uint4*)(rowp + ((((unsigned)(h * 4 + q)) << 4) ^ swz)) = u;
            uint4 ud;
            ud.x = pack2bf(aj[q * 8 + 0] - ai[q * 8 + 0], aj[q * 8 + 1] - ai[q * 8 + 1]);
            ud.y = pack2bf(aj[q * 8 + 2] - ai[q * 8 + 2], aj[q * 8 + 3] - ai[q * 8 + 3]);
            ud.z = pack2bf(aj[q * 8 + 4] - ai[q * 8 + 4], aj[q * 8 + 5] - ai[q * 8 + 5]);
            ud.w = pack2bf(aj[q * 8 + 6] - ai[q * 8 + 6], aj[q * 8 + 7] - ai[q * 8 + 7]);
            *(uint4*)(rowp + ((((unsigned)(8 + h * 4 + q)) << 4) ^ swz)) = ud;
        }
    }

    // ---------------- weight fragments ----------------
    bf16x8 w1f[4][4];
    bf16x8 w2f[4][2];
    {
        const bf16x8* wsv = (const bf16x8*)wbf;
        #pragma unroll
        for (int ct = 0; ct < 4; ++ct)
            #pragma unroll
            for (int kt = 0; kt < 4; ++kt)
                w1f[ct][kt] = wsv[(ct * 16 + ln) * 16 + kt * 4 + rg];
        #pragma unroll
        for (int ot = 0; ot < 4; ++ot)
            #pragma unroll
            for (int kt = 0; kt < 2; ++kt)
                w2f[ot][kt] = wsv[1024 + (ot * 16 + ln) * 8 + kt * 4 + rg];
    }

    __syncthreads();

    // ---------------- GEMM1: H1^T = W1^T @ F^T (wave-local rows) ----------------
    f32x4 acc[2][4];
    #pragma unroll
    for (int eti = 0; eti < 2; ++eti)
        #pragma unroll
        for (int ct = 0; ct < 4; ++ct)
            acc[eti][ct] = (f32x4){0.f, 0.f, 0.f, 0.f};

    #pragma unroll
    for (int kt = 0; kt < 4; ++kt) {
        #pragma unroll
        for (int eti = 0; eti < 2; ++eti) {
            const int e = (w * 2 + eti) * 16 + ln;
            bf16x8 bf = *(const bf16x8*)(sF + e * 256 +
                           (((unsigned)(kt * 64 + rg * 16)) ^ ((unsigned)(e & 7) << 4)));
            #pragma unroll
            for (int ct = 0; ct < 4; ++ct)
                acc[eti][ct] = __builtin_amdgcn_mfma_f32_16x16x32_bf16(
                    w1f[ct][kt], bf, acc[eti][ct], 0, 0, 0);
        }
    }

    // ---------------- epilogue1: bias+relu -> bf16 -> sH (wave-local) ----------------
    #pragma unroll
    for (int eti = 0; eti < 2; ++eti) {
        const int e = (w * 2 + eti) * 16 + ln;
        unsigned char* rowp = sH + e * 128;
        const unsigned int swz = (unsigned int)(e & 7) << 4;
        #pragma unroll
        for (int ct = 0; ct < 4; ++ct) {
            const int c0 = ct * 16 + rg * 4;
            float v0 = fmaxf(acc[eti][ct][0] + b1[c0 + 0], 0.f);
            float v1 = fmaxf(acc[eti][ct][1] + b1[c0 + 1], 0.f);
            float v2 = fmaxf(acc[eti][ct][2] + b1[c0 + 2], 0.f);
            float v3 = fmaxf(acc[eti][ct][3] + b1[c0 + 3], 0.f);
            uint2 u;
            u.x = pack2bf(v0, v1);
            u.y = pack2bf(v2, v3);
            *(uint2*)(rowp + (((unsigned)(c0 * 2)) ^ swz)) = u;
        }
    }

    // ---------------- GEMM2: H2^T = W2^T @ H1^T (wave-local) ----------------
    f32x4 acc2[2][4];
    #pragma unroll
    for (int eti = 0; eti < 2; ++eti)
        #pragma unroll
        for (int ot = 0; ot < 4; ++ot)
            acc2[eti][ot] = (f32x4){0.f, 0.f, 0.f, 0.f};

    #pragma unroll
    for (int kt = 0; kt < 2; ++kt) {
        #pragma unroll
        for (int eti = 0; eti < 2; ++eti) {
            const int e = (w * 2 + eti) * 16 + ln;
            bf16x8 bf = *(const bf16x8*)(sH + e * 128 +
                           (((unsigned)(kt * 64 + rg * 16)) ^ ((unsigned)(e & 7) << 4)));
            #pragma unroll
            for (int ot = 0; ot < 4; ++ot)
                acc2[eti][ot] = __builtin_amdgcn_mfma_f32_16x16x32_bf16(
                    w2f[ot][kt], bf, acc2[eti][ot], 0, 0, 0);
        }
    }

    // ---------------- epilogue2: bias+relu -> f32 into sF (reused, wave-local rows) ----------------
    #pragma unroll
    for (int eti = 0; eti < 2; ++eti) {
        const int e = (w * 2 + eti) * 16 + ln;
        unsigned char* rowp = sF + e * 256;
        const unsigned int swz = (unsigned int)(e & 7) << 4;
        #pragma unroll
        for (int ot = 0; ot < 4; ++ot) {
            const int c0 = ot * 16 + rg * 4;
            f32x4 v;
            v[0] = fmaxf(acc2[eti][ot][0] + b2[c0 + 0], 0.f);
            v[1] = fmaxf(acc2[eti][ot][1] + b2[c0 + 1], 0.f);
            v[2] = fmaxf(acc2[eti][ot][2] + b2[c0 + 2], 0.f);
            v[3] = fmaxf(acc2[eti][ot][3] + b2[c0 + 3], 0.f);
            *(f32x4*)(rowp + (((unsigned)(c0 * 4)) ^ swz)) = v;
        }
    }

    __syncthreads();

    // ---------------- segmented max over dst groups ----------------
    {
        const int dfirst = csr_dst[p0];
        const int dlast  = csr_dst[p1 - 1];
        const int c = tid & 63;
        for (int d = dfirst + (tid >> 6); d <= dlast; d += 4) {
            const int s0 = starts[d], s1 = starts[d + 1];
            const int lo = max(s0, p0), hi = min(s1, p1);
            if (lo >= hi) continue;  // zero-edge node between groups
            float m = 0.0f;          // relu >= 0; empty -> 0 matches reference
            for (int p = lo; p < hi; ++p) {
                const int e = p - p0;
                m = fmaxf(m, *(const float*)(sF + e * 256 +
                            (((unsigned)(c * 4)) ^ ((unsigned)(e & 7) << 4))));
            }
            if (s0 >= p0 && s1 <= p1)
                out[(long)d * 64 + c] = m;                              // sole owner
            else
                atomicMax((int*)out + (long)d * 64 + c, __float_as_int(m));  // boundary
        }
    }
}

extern "C" void kernel_launch(void* const* d_in, const int* in_sizes, int n_in,
                              void* d_out, int out_size, void* d_ws, size_t ws_size,
                              hipStream_t stream) {
    const float* x  = (const float*)d_in[0];
    const int*   ei = (const int*)d_in[1];
    const float* W1 = (const float*)d_in[2];
    const float* b1 = (const float*)d_in[3];
    const float* W2 = (const float*)d_in[4];
    const float* b2 = (const float*)d_in[5];
    float* out = (float*)d_out;

    const int E = in_sizes[1] / 2;
    const int N = in_sizes[0] / 64;

    int* wsI = (int*)d_ws;
    int* counts  = wsI + OFF_COUNTS;
    int* cursor  = wsI + OFF_CURSOR;
    int* starts  = wsI + OFF_STARTS;
    int* bsum    = wsI + OFF_BSUM;
    int* csr_src = wsI + OFF_CSR;
    int* csr_dst = wsI + OFF_CSR + E;
    unsigned short* wbf = (unsigned short*)(wsI + OFF_CSR + 2 * E);

    hipMemsetAsync(d_out, 0, (size_t)out_size * sizeof(float), stream);
    hipMemsetAsync(counts, 0, 2u * 100000u * sizeof(int), stream);  // counts + cursor

    prep_weights_kernel<<<48, 256, 0, stream>>>(W1, W2, wbf);

    const int nbE = (E + 255) / 256;
    hist_kernel<<<nbE, 256, 0, stream>>>(ei, counts, E);

    const int nb2 = (N + NSCAN - 1) / NSCAN;
    scanA_kernel<<<nb2, 256, 0, stream>>>(counts, bsum, N);
    scanB_kernel<<<1, 64, 0, stream>>>(bsum, starts, nb2, N, E);
    scanC_kernel<<<nb2, 256, 0, stream>>>(counts, bsum, starts, N);

    scatter_kernel<<<nbE, 256, 0, stream>>>(ei, starts, cursor, csr_src, csr_dst, E);

    const int nb = (E + EB - 1) / EB;
    edgeconv_kernel<<<nb, 256, 0, stream>>>(x, csr_src, csr_dst, starts, b1, b2, wbf, out, E);
}